// Round 1
// baseline (4170.803 us; speedup 1.0000x reference)
//
#include <hip/hip_runtime.h>
#include <math.h>

#define NB 8
#define NN 1024
#define NK 8
#define ND 256
#define ND2 512
#define NBK 64
#define EPSA 1e-8f
#define LNEPS 1e-5f
#define GSTEP (2.0f/31.0f)

// ---------------- LN stats (mean, rstd) per input row ----------------
__global__ __launch_bounds__(256) void k_ln_stats(const float* __restrict__ inp,
                                                  float* __restrict__ stats) {
  const int row = blockIdx.x;  // 0..B*N-1
  const int t = threadIdx.x;
  const float v = inp[(size_t)row * ND + t];
  float s = v, ss = v * v;
#pragma unroll
  for (int m = 32; m >= 1; m >>= 1) { s += __shfl_xor(s, m); ss += __shfl_xor(ss, m); }
  __shared__ float red[8];
  const int wv = t >> 6;
  if ((t & 63) == 0) { red[wv] = s; red[4 + wv] = ss; }
  __syncthreads();
  if (t == 0) {
    const float S = red[0] + red[1] + red[2] + red[3];
    const float SS = red[4] + red[5] + red[6] + red[7];
    const float mean = S * (1.0f / ND);
    const float var = SS * (1.0f / ND) - mean * mean;
    stats[row * 2 + 0] = mean;
    stats[row * 2 + 1] = rsqrtf(var + LNEPS);
  }
}

// ---------------- k = LN(x)@wk, v = LN(x)@wv  (fused LN via stats) ----------------
__global__ __launch_bounds__(256) void k_gemm_kv(
    const float* __restrict__ inp, const float* __restrict__ stats,
    const float* __restrict__ nig, const float* __restrict__ nib,
    const float* __restrict__ wk, const float* __restrict__ wv,
    float* __restrict__ kout, float* __restrict__ vout) {
  const float* __restrict__ W = blockIdx.z ? wv : wk;
  float* __restrict__ out = blockIdx.z ? vout : kout;
  const int row0 = blockIdx.x * 64;
  const int col0 = blockIdx.y * 64;
  const int t = threadIdx.x;
  __shared__ float As[16][64];
  __shared__ float Bs[16][68];
  const int alr = t >> 2;
  const int alc = (t & 3) * 4;
  const int blr = t >> 4;
  const int blc = (t & 15) * 4;
  const int ty = t >> 4, tx = t & 15;
  float acc[4][4] = {};
  const float m = stats[(row0 + alr) * 2 + 0];
  const float rs = stats[(row0 + alr) * 2 + 1];
  for (int kk = 0; kk < ND; kk += 16) {
    {
      const float4 xv = *(const float4*)(inp + (size_t)(row0 + alr) * ND + kk + alc);
      const float4 gg = *(const float4*)(nig + kk + alc);
      const float4 bb = *(const float4*)(nib + kk + alc);
      As[alc + 0][alr] = (xv.x - m) * rs * gg.x + bb.x;
      As[alc + 1][alr] = (xv.y - m) * rs * gg.y + bb.y;
      As[alc + 2][alr] = (xv.z - m) * rs * gg.z + bb.z;
      As[alc + 3][alr] = (xv.w - m) * rs * gg.w + bb.w;
      *(float4*)&Bs[blr][blc] = *(const float4*)(W + (size_t)(kk + blr) * ND + col0 + blc);
    }
    __syncthreads();
#pragma unroll
    for (int kq = 0; kq < 16; kq++) {
      const float4 a4 = *(const float4*)&As[kq][ty * 4];
      const float4 b4 = *(const float4*)&Bs[kq][tx * 4];
      const float a[4] = {a4.x, a4.y, a4.z, a4.w};
      const float bv[4] = {b4.x, b4.y, b4.z, b4.w};
#pragma unroll
      for (int i = 0; i < 4; i++)
#pragma unroll
        for (int j = 0; j < 4; j++)
          acc[i][j] = fmaf(a[i], bv[j], acc[i][j]);
    }
    __syncthreads();
  }
#pragma unroll
  for (int i = 0; i < 4; i++) {
    float4 o = {acc[i][0], acc[i][1], acc[i][2], acc[i][3]};
    *(float4*)(out + (size_t)(row0 + ty * 4 + i) * ND + col0 + tx * 4) = o;
  }
}

// ---------------- per-(b,k): pos/scl extraction + q = LN(slots)@wq ----------------
__global__ __launch_bounds__(256) void k_prep(
    const float* __restrict__ sf, const float* __restrict__ nsg,
    const float* __restrict__ nsb, const float* __restrict__ wq,
    float* __restrict__ q, float* __restrict__ pos, float* __restrict__ scl) {
  const int bk = blockIdx.x;
  const int t = threadIdx.x;
  const float v = sf[bk * 260 + t];
  float s = v, ss = v * v;
#pragma unroll
  for (int m = 32; m >= 1; m >>= 1) { s += __shfl_xor(s, m); ss += __shfl_xor(ss, m); }
  __shared__ float red[8];
  __shared__ float lnv[256];
  const int wv = t >> 6;
  if ((t & 63) == 0) { red[wv] = s; red[4 + wv] = ss; }
  __syncthreads();
  const float S = red[0] + red[1] + red[2] + red[3];
  const float SS = red[4] + red[5] + red[6] + red[7];
  const float mean = S * (1.0f / ND);
  const float var = SS * (1.0f / ND) - mean * mean;
  const float rstd = rsqrtf(var + LNEPS);
  lnv[t] = (v - mean) * rstd * nsg[t] + nsb[t];
  if (t < 2) {
    const float p = sf[bk * 260 + 256 + t];
    pos[bk * 2 + t] = fminf(fmaxf(p, -1.0f), 1.0f);
    const float sc = sf[bk * 260 + 258 + t];
    scl[bk * 2 + t] = fminf(fmaxf(sc, 1e-3f), 2.0f);
  }
  __syncthreads();
  float acc = 0.f;
  for (int e = 0; e < ND; e++) acc = fmaf(lnv[e], wq[e * ND + t], acc);
  q[bk * ND + t] = acc;
}

// ---------------- fused grid_enc pass ----------------
// mode 0: dots[bk][n] = q . grid_enc(k + rel_enc) * 1/16
// mode 1: upd[bk][d] += attn[bk][n] * grid_enc(v + rel_enc)[n][d]
__global__ __launch_bounds__(256) void k_fused_pass(
    const float* __restrict__ kv,
    const float* __restrict__ pos, const float* __restrict__ scl,
    const float* __restrict__ gpw, const float* __restrict__ gpb,
    const float* __restrict__ lng, const float* __restrict__ lnb,
    const float* __restrict__ w1, const float* __restrict__ b1,
    const float* __restrict__ w2, const float* __restrict__ b2,
    const float* __restrict__ q, float* __restrict__ dots,
    const float* __restrict__ attn0, const float* __restrict__ denom,
    float* __restrict__ upd, const int mode) {
  __shared__ float tlnT[ND][20];   // [d][row], pad 20 keeps 16B alignment
  __shared__ float h1T[ND2][20];   // [j][row]
  const int bk = blockIdx.y;
  const int n0 = blockIdx.x * 16;
  const int b = bk >> 3;
  const int t = threadIdx.x;

  // ---- Phase A: t = kv + rel_enc ; LN -> tlnT ----
  {
    const float p0 = pos[bk * 2 + 0], p1 = pos[bk * 2 + 1];
    const float s0 = scl[bk * 2 + 0] * 5.0f, s1 = scl[bk * 2 + 1] * 5.0f;
    const int r = t >> 4;
    const int l16 = t & 15;
    const int n = n0 + r;
    const float gx = -1.0f + GSTEP * (float)(n >> 5);
    const float gy = -1.0f + GSTEP * (float)(n & 31);
    const float rg0 = (gx - p0) / s0;
    const float rg1 = (gy - p1) / s1;
    const float* kvrow = kv + ((size_t)(b * NN + n)) * ND;
    const int dbase = l16 * 16;
    float tv[16];
    float sum = 0.f, ssq = 0.f;
#pragma unroll
    for (int ii = 0; ii < 4; ii++) {
      const int d = dbase + ii * 4;
      const float4 kv4 = *(const float4*)(kvrow + d);
      const float4 wa = *(const float4*)(gpw + d);
      const float4 wb = *(const float4*)(gpw + ND + d);
      const float4 pb = *(const float4*)(gpb + d);
      float v0 = kv4.x + rg0 * wa.x + rg1 * wb.x + pb.x;
      float v1 = kv4.y + rg0 * wa.y + rg1 * wb.y + pb.y;
      float v2 = kv4.z + rg0 * wa.z + rg1 * wb.z + pb.z;
      float v3 = kv4.w + rg0 * wa.w + rg1 * wb.w + pb.w;
      tv[ii * 4 + 0] = v0; sum += v0; ssq += v0 * v0;
      tv[ii * 4 + 1] = v1; sum += v1; ssq += v1 * v1;
      tv[ii * 4 + 2] = v2; sum += v2; ssq += v2 * v2;
      tv[ii * 4 + 3] = v3; sum += v3; ssq += v3 * v3;
    }
#pragma unroll
    for (int m = 8; m >= 1; m >>= 1) { sum += __shfl_xor(sum, m); ssq += __shfl_xor(ssq, m); }
    const float mean = sum * (1.0f / ND);
    const float var = ssq * (1.0f / ND) - mean * mean;
    const float rstd = rsqrtf(var + LNEPS);
#pragma unroll
    for (int ii = 0; ii < 4; ii++) {
      const int d = dbase + ii * 4;
      const float4 gg = *(const float4*)(lng + d);
      const float4 bb = *(const float4*)(lnb + d);
      tlnT[d + 0][r] = (tv[ii * 4 + 0] - mean) * rstd * gg.x + bb.x;
      tlnT[d + 1][r] = (tv[ii * 4 + 1] - mean) * rstd * gg.y + bb.y;
      tlnT[d + 2][r] = (tv[ii * 4 + 2] - mean) * rstd * gg.z + bb.z;
      tlnT[d + 3][r] = (tv[ii * 4 + 3] - mean) * rstd * gg.w + bb.w;
    }
  }
  __syncthreads();

  const int cg = t & 63;
  const int rg = t >> 6;

  // ---- Phase B: h1 = relu(tln @ W1 + b1), 8 cols x 4 rows per thread ----
  float accB[4][8];
#pragma unroll
  for (int i = 0; i < 4; i++)
#pragma unroll
    for (int j = 0; j < 8; j++) accB[i][j] = 0.f;
  for (int d = 0; d < ND; d++) {
    const float4 a4 = *(const float4*)&tlnT[d][rg * 4];
    const float4 wA = *(const float4*)(w1 + (size_t)d * ND2 + cg * 8);
    const float4 wB = *(const float4*)(w1 + (size_t)d * ND2 + cg * 8 + 4);
    const float a[4] = {a4.x, a4.y, a4.z, a4.w};
    const float w[8] = {wA.x, wA.y, wA.z, wA.w, wB.x, wB.y, wB.z, wB.w};
#pragma unroll
    for (int i = 0; i < 4; i++)
#pragma unroll
      for (int j = 0; j < 8; j++)
        accB[i][j] = fmaf(a[i], w[j], accB[i][j]);
  }
  {
    const float4 bA = *(const float4*)(b1 + cg * 8);
    const float4 bB = *(const float4*)(b1 + cg * 8 + 4);
    const float bb[8] = {bA.x, bA.y, bA.z, bA.w, bB.x, bB.y, bB.z, bB.w};
#pragma unroll
    for (int j = 0; j < 8; j++) {
      float4 hv;
      hv.x = fmaxf(accB[0][j] + bb[j], 0.f);
      hv.y = fmaxf(accB[1][j] + bb[j], 0.f);
      hv.z = fmaxf(accB[2][j] + bb[j], 0.f);
      hv.w = fmaxf(accB[3][j] + bb[j], 0.f);
      *(float4*)&h1T[cg * 8 + j][rg * 4] = hv;
    }
  }
  __syncthreads();

  // ---- Phase C: o = h1 @ W2 + b2, 4 cols x 4 rows per thread ----
  float accC[4][4];
#pragma unroll
  for (int i = 0; i < 4; i++)
#pragma unroll
    for (int c = 0; c < 4; c++) accC[i][c] = 0.f;
  for (int j = 0; j < ND2; j++) {
    const float4 a4 = *(const float4*)&h1T[j][rg * 4];
    const float4 w4 = *(const float4*)(w2 + (size_t)j * ND + cg * 4);
    const float a[4] = {a4.x, a4.y, a4.z, a4.w};
    const float w[4] = {w4.x, w4.y, w4.z, w4.w};
#pragma unroll
    for (int i = 0; i < 4; i++)
#pragma unroll
      for (int c = 0; c < 4; c++)
        accC[i][c] = fmaf(a[i], w[c], accC[i][c]);
  }
  const float4 b4 = *(const float4*)(b2 + cg * 4);
  float o[4][4];
#pragma unroll
  for (int i = 0; i < 4; i++) {
    o[i][0] = accC[i][0] + b4.x;
    o[i][1] = accC[i][1] + b4.y;
    o[i][2] = accC[i][2] + b4.z;
    o[i][3] = accC[i][3] + b4.w;
  }

  if (mode == 0) {
    const float4 q4 = *(const float4*)(q + bk * ND + cg * 4);
    float part[4];
#pragma unroll
    for (int i = 0; i < 4; i++)
      part[i] = o[i][0] * q4.x + o[i][1] * q4.y + o[i][2] * q4.z + o[i][3] * q4.w;
#pragma unroll
    for (int m = 32; m >= 1; m >>= 1) {
#pragma unroll
      for (int i = 0; i < 4; i++) part[i] += __shfl_xor(part[i], m);
    }
    if ((t & 63) == 0) {
#pragma unroll
      for (int i = 0; i < 4; i++)
        dots[bk * NN + n0 + rg * 4 + i] = part[i] * 0.0625f;
    }
  } else {
    const float dn = denom[bk];
    float aw[4];
#pragma unroll
    for (int i = 0; i < 4; i++)
      aw[i] = (attn0[bk * NN + n0 + rg * 4 + i] + EPSA) / dn;
#pragma unroll
    for (int c = 0; c < 4; c++) {
      const float v = aw[0] * o[0][c] + aw[1] * o[1][c] + aw[2] * o[2][c] + aw[3] * o[3][c];
      atomicAdd(upd + bk * ND + cg * 4 + c, v);
    }
  }
}

// ---------------- softmax over K per (b,n) ----------------
__global__ __launch_bounds__(256) void k_softmax(const float* __restrict__ dots,
                                                 float* __restrict__ attn0) {
  const int idx = blockIdx.x * 256 + threadIdx.x;  // b*N + n
  const int b = idx >> 10, n = idx & 1023;
  float vals[NK];
  float mx = -1e30f;
#pragma unroll
  for (int k = 0; k < NK; k++) {
    vals[k] = dots[(size_t)(b * NK + k) * NN + n];
    mx = fmaxf(mx, vals[k]);
  }
  float s = 0.f;
#pragma unroll
  for (int k = 0; k < NK; k++) { vals[k] = expf(vals[k] - mx); s += vals[k]; }
  const float inv = 1.0f / s;
#pragma unroll
  for (int k = 0; k < NK; k++)
    attn0[(size_t)(b * NK + k) * NN + n] = vals[k] * inv;
}

// ---------------- attn0 row sums -> denom, pos_n (into sf tail) ----------------
__global__ __launch_bounds__(256) void k_reduce1(const float* __restrict__ attn0,
                                                 float* __restrict__ sf,
                                                 float* __restrict__ denom) {
  const int bk = blockIdx.x, t = threadIdx.x;
  float S = 0.f, G0 = 0.f, G1 = 0.f;
#pragma unroll
  for (int i = 0; i < 4; i++) {
    const int n = t + 256 * i;
    const float a = attn0[(size_t)bk * NN + n];
    const float gx = -1.0f + GSTEP * (float)(n >> 5);
    const float gy = -1.0f + GSTEP * (float)(n & 31);
    S += a; G0 = fmaf(a, gx, G0); G1 = fmaf(a, gy, G1);
  }
#pragma unroll
  for (int m = 32; m >= 1; m >>= 1) {
    S += __shfl_xor(S, m); G0 += __shfl_xor(G0, m); G1 += __shfl_xor(G1, m);
  }
  __shared__ float red[12];
  const int wv = t >> 6;
  if ((t & 63) == 0) { red[wv] = S; red[4 + wv] = G0; red[8 + wv] = G1; }
  __syncthreads();
  if (t == 0) {
    const float St = red[0] + red[1] + red[2] + red[3];
    const float G0t = red[4] + red[5] + red[6] + red[7];
    const float G1t = red[8] + red[9] + red[10] + red[11];
    denom[bk] = St + (float)NN * EPSA;
    sf[bk * 260 + 256] = G0t;
    sf[bk * 260 + 257] = G1t;
  }
}

// ---------------- scl_n (into sf tail) ----------------
__global__ __launch_bounds__(256) void k_reduce2(const float* __restrict__ attn0,
                                                 float* __restrict__ sf) {
  const int bk = blockIdx.x, t = threadIdx.x;
  const float p0 = sf[bk * 260 + 256];
  const float p1 = sf[bk * 260 + 257];
  float S0 = 0.f, S1 = 0.f;
#pragma unroll
  for (int i = 0; i < 4; i++) {
    const int n = t + 256 * i;
    const float w = attn0[(size_t)bk * NN + n] + EPSA;
    const float d0 = (-1.0f + GSTEP * (float)(n >> 5)) - p0;
    const float d1 = (-1.0f + GSTEP * (float)(n & 31)) - p1;
    S0 = fmaf(w, d0 * d0, S0);
    S1 = fmaf(w, d1 * d1, S1);
  }
#pragma unroll
  for (int m = 32; m >= 1; m >>= 1) { S0 += __shfl_xor(S0, m); S1 += __shfl_xor(S1, m); }
  __shared__ float red[8];
  const int wv = t >> 6;
  if ((t & 63) == 0) { red[wv] = S0; red[4 + wv] = S1; }
  __syncthreads();
  if (t == 0) {
    const float s0 = sqrtf(red[0] + red[1] + red[2] + red[3]);
    const float s1 = sqrtf(red[4] + red[5] + red[6] + red[7]);
    sf[bk * 260 + 258] = fminf(fmaxf(s0, 1e-3f), 2.0f);
    sf[bk * 260 + 259] = fminf(fmaxf(s1, 1e-3f), 2.0f);
  }
}

// ---------------- GRU slot update ----------------
__global__ __launch_bounds__(256) void k_gru(const float* __restrict__ upd,
                                             float* __restrict__ sf,
                                             const float* __restrict__ wih,
                                             const float* __restrict__ whh,
                                             const float* __restrict__ bih,
                                             const float* __restrict__ bhh) {
  const int bk = blockIdx.x, t = threadIdx.x;
  __shared__ float u[256], h[256];
  u[t] = upd[bk * ND + t];
  h[t] = sf[bk * 260 + t];
  __syncthreads();
  float g[6];
#pragma unroll
  for (int s = 0; s < 3; s++) {
    float ax = 0.f, ah = 0.f;
    const float* wi = wih + (size_t)(s * ND + t) * ND;
    const float* wh = whh + (size_t)(s * ND + t) * ND;
    for (int d = 0; d < ND; d++) {
      ax = fmaf(u[d], wi[d], ax);
      ah = fmaf(h[d], wh[d], ah);
    }
    g[s] = ax + bih[s * ND + t];
    g[3 + s] = ah + bhh[s * ND + t];
  }
  const float r = 1.0f / (1.0f + expf(-(g[0] + g[3])));
  const float z = 1.0f / (1.0f + expf(-(g[1] + g[4])));
  const float nn = tanhf(g[2] + r * g[5]);
  sf[bk * 260 + t] = (1.0f - z) * nn + z * h[t];
}

// ---------------- rel_grid output (last step's pos/scl) ----------------
__global__ __launch_bounds__(256) void k_relgrid(const float* __restrict__ pos,
                                                 const float* __restrict__ scl,
                                                 float* __restrict__ outr) {
  const int bk = blockIdx.x, t = threadIdx.x;
  const float p0 = pos[bk * 2 + 0], p1 = pos[bk * 2 + 1];
  const float s0 = scl[bk * 2 + 0] * 5.0f, s1 = scl[bk * 2 + 1] * 5.0f;
#pragma unroll
  for (int i = 0; i < 4; i++) {
    const int n = t + 256 * i;
    const float gx = -1.0f + GSTEP * (float)(n >> 5);
    const float gy = -1.0f + GSTEP * (float)(n & 31);
    float2 v;
    v.x = (gx - p0) / s0;
    v.y = (gy - p1) / s1;
    *(float2*)(outr + ((size_t)bk * NN + n) * 2) = v;
  }
}

// ---------------- final copies: conditioning + attn0 ----------------
__global__ __launch_bounds__(256) void k_copyout(const float* __restrict__ sf,
                                                 const float* __restrict__ attn0,
                                                 float* __restrict__ out) {
  const int i = blockIdx.x * 256 + threadIdx.x;
  if (i < 16640) out[i] = sf[i];
  if (i < 65536) out[16640 + i] = attn0[i];
}

extern "C" void kernel_launch(void* const* d_in, const int* in_sizes, int n_in,
                              void* d_out, int out_size, void* d_ws, size_t ws_size,
                              hipStream_t stream) {
  const float* inputs   = (const float*)d_in[0];
  const float* cond     = (const float*)d_in[1];
  const float* ni_g     = (const float*)d_in[2];
  const float* ni_b     = (const float*)d_in[3];
  const float* ns_g     = (const float*)d_in[4];
  const float* ns_b     = (const float*)d_in[5];
  const float* wq       = (const float*)d_in[6];
  const float* wk       = (const float*)d_in[7];
  const float* wv       = (const float*)d_in[8];
  const float* gp_w     = (const float*)d_in[9];
  const float* gp_b     = (const float*)d_in[10];
  const float* ge_ln_g  = (const float*)d_in[11];
  const float* ge_ln_b  = (const float*)d_in[12];
  const float* ge_w1    = (const float*)d_in[13];
  const float* ge_b1    = (const float*)d_in[14];
  const float* ge_w2    = (const float*)d_in[15];
  const float* ge_b2    = (const float*)d_in[16];
  const float* gru_wih  = (const float*)d_in[17];
  const float* gru_whh  = (const float*)d_in[18];
  const float* gru_bih  = (const float*)d_in[19];
  const float* gru_bhh  = (const float*)d_in[20];

  float* ws   = (float*)d_ws;
  float* kbuf = ws;                  // 8*1024*256
  float* vbuf = kbuf + 2097152;      // 8*1024*256
  float* sf   = vbuf + 2097152;      // 64*260
  float* qb   = sf + 16640;          // 64*256
  float* posb = qb + 16384;          // 64*2 (padded)
  float* sclb = posb + 128;          // 64*2 (padded)
  float* dotsb = sclb + 128;         // 64*1024
  float* at0  = dotsb + 65536;       // 64*1024
  float* denb = at0 + 65536;         // 64
  float* updb = denb + 64;           // 64*256
  float* statb = updb + 16384;       // 8192*2

  float* out = (float*)d_out;

  // slots_full working copy
  hipMemcpyAsync(sf, cond, 16640 * sizeof(float), hipMemcpyDeviceToDevice, stream);

  // LN stats + k/v projections (once)
  k_ln_stats<<<NB * NN, 256, 0, stream>>>(inputs, statb);
  k_gemm_kv<<<dim3(128, 4, 2), 256, 0, stream>>>(inputs, statb, ni_g, ni_b, wk, wv, kbuf, vbuf);

  for (int s = 0; s < 4; s++) {
    k_prep<<<NBK, 256, 0, stream>>>(sf, ns_g, ns_b, wq, qb, posb, sclb);
    k_fused_pass<<<dim3(64, NBK), 256, 0, stream>>>(
        kbuf, posb, sclb, gp_w, gp_b, ge_ln_g, ge_ln_b, ge_w1, ge_b1, ge_w2, ge_b2,
        qb, dotsb, nullptr, nullptr, nullptr, 0);
    k_softmax<<<32, 256, 0, stream>>>(dotsb, at0);
    k_reduce1<<<NBK, 256, 0, stream>>>(at0, sf, denb);
    k_reduce2<<<NBK, 256, 0, stream>>>(at0, sf);
    if (s < 3) {
      hipMemsetAsync(updb, 0, 16384 * sizeof(float), stream);
      k_fused_pass<<<dim3(64, NBK), 256, 0, stream>>>(
          vbuf, posb, sclb, gp_w, gp_b, ge_ln_g, ge_ln_b, ge_w1, ge_b1, ge_w2, ge_b2,
          nullptr, nullptr, at0, denb, updb, 1);
      k_gru<<<NBK, 256, 0, stream>>>(updb, sf, gru_wih, gru_whh, gru_bih, gru_bhh);
    }
  }

  // outputs: [conditioning 16640][attn0 65536][rel_grid 131072]
  k_relgrid<<<NBK, 256, 0, stream>>>(posb, sclb, out + 16640 + 65536);
  k_copyout<<<256, 256, 0, stream>>>(sf, at0, out);
}

// Round 2
// 879.133 us; speedup vs baseline: 4.7442x; 4.7442x over previous
//
#include <hip/hip_runtime.h>
#include <math.h>

#define NB 8
#define NN 1024
#define NK 8
#define ND 256
#define ND2 512
#define NBK 64
#define EPSA 1e-8f
#define LNEPS 1e-5f
#define GSTEP (2.0f/31.0f)

using short8 = __attribute__((ext_vector_type(8))) short;
using short4v = __attribute__((ext_vector_type(4))) short;
using floatx4 = __attribute__((ext_vector_type(4))) float;

__device__ __forceinline__ short f2bf(float f) {
  unsigned u = __builtin_bit_cast(unsigned, f);
  u += 0x7fffu + ((u >> 16) & 1u);
  return (short)(u >> 16);
}

// ---------------- LN stats (mean, rstd) per input row ----------------
__global__ __launch_bounds__(256) void k_ln_stats(const float* __restrict__ inp,
                                                  float* __restrict__ stats) {
  const int row = blockIdx.x;
  const int t = threadIdx.x;
  const float v = inp[(size_t)row * ND + t];
  float s = v, ss = v * v;
#pragma unroll
  for (int m = 32; m >= 1; m >>= 1) { s += __shfl_xor(s, m); ss += __shfl_xor(ss, m); }
  __shared__ float red[8];
  const int wv = t >> 6;
  if ((t & 63) == 0) { red[wv] = s; red[4 + wv] = ss; }
  __syncthreads();
  if (t == 0) {
    const float S = red[0] + red[1] + red[2] + red[3];
    const float SS = red[4] + red[5] + red[6] + red[7];
    const float mean = S * (1.0f / ND);
    const float var = SS * (1.0f / ND) - mean * mean;
    stats[row * 2 + 0] = mean;
    stats[row * 2 + 1] = rsqrtf(var + LNEPS);
  }
}

// ---------------- k = LN(x)@wk, v = LN(x)@wv ----------------
__global__ __launch_bounds__(256) void k_gemm_kv(
    const float* __restrict__ inp, const float* __restrict__ stats,
    const float* __restrict__ nig, const float* __restrict__ nib,
    const float* __restrict__ wk, const float* __restrict__ wv,
    float* __restrict__ kout, float* __restrict__ vout) {
  const float* __restrict__ W = blockIdx.z ? wv : wk;
  float* __restrict__ out = blockIdx.z ? vout : kout;
  const int row0 = blockIdx.x * 64;
  const int col0 = blockIdx.y * 64;
  const int t = threadIdx.x;
  __shared__ float As[16][64];
  __shared__ float Bs[16][68];
  const int alr = t >> 2;
  const int alc = (t & 3) * 4;
  const int blr = t >> 4;
  const int blc = (t & 15) * 4;
  const int ty = t >> 4, tx = t & 15;
  float acc[4][4] = {};
  const float m = stats[(row0 + alr) * 2 + 0];
  const float rs = stats[(row0 + alr) * 2 + 1];
  for (int kk = 0; kk < ND; kk += 16) {
    {
      const float4 xv = *(const float4*)(inp + (size_t)(row0 + alr) * ND + kk + alc);
      const float4 gg = *(const float4*)(nig + kk + alc);
      const float4 bb = *(const float4*)(nib + kk + alc);
      As[alc + 0][alr] = (xv.x - m) * rs * gg.x + bb.x;
      As[alc + 1][alr] = (xv.y - m) * rs * gg.y + bb.y;
      As[alc + 2][alr] = (xv.z - m) * rs * gg.z + bb.z;
      As[alc + 3][alr] = (xv.w - m) * rs * gg.w + bb.w;
      *(float4*)&Bs[blr][blc] = *(const float4*)(W + (size_t)(kk + blr) * ND + col0 + blc);
    }
    __syncthreads();
#pragma unroll
    for (int kq = 0; kq < 16; kq++) {
      const float4 a4 = *(const float4*)&As[kq][ty * 4];
      const float4 b4 = *(const float4*)&Bs[kq][tx * 4];
      const float a[4] = {a4.x, a4.y, a4.z, a4.w};
      const float bv[4] = {b4.x, b4.y, b4.z, b4.w};
#pragma unroll
      for (int i = 0; i < 4; i++)
#pragma unroll
        for (int j = 0; j < 4; j++)
          acc[i][j] = fmaf(a[i], bv[j], acc[i][j]);
    }
    __syncthreads();
  }
#pragma unroll
  for (int i = 0; i < 4; i++) {
    float4 o = {acc[i][0], acc[i][1], acc[i][2], acc[i][3]};
    *(float4*)(out + (size_t)(row0 + ty * 4 + i) * ND + col0 + tx * 4) = o;
  }
}

// ---------------- weight transpose + bf16 convert: dst[n][k] = bf16(src[k][n]) ----------------
__global__ __launch_bounds__(256) void k_cvtT(const float* __restrict__ src,
                                              short* __restrict__ dst,
                                              const int kshift, const int kmask,
                                              const int Nsrc) {
  const int idx = blockIdx.x * 256 + threadIdx.x;
  const int n = idx >> kshift;
  const int k = idx & kmask;
  dst[idx] = f2bf(src[(size_t)k * Nsrc + n]);
}

// ---------------- per-(b,k): pos/scl extraction + q = LN(slots)@wq ----------------
__global__ __launch_bounds__(256) void k_prep(
    const float* __restrict__ sf, const float* __restrict__ nsg,
    const float* __restrict__ nsb, const float* __restrict__ wq,
    float* __restrict__ q, float* __restrict__ pos, float* __restrict__ scl) {
  const int bk = blockIdx.x;
  const int t = threadIdx.x;
  const float v = sf[bk * 260 + t];
  float s = v, ss = v * v;
#pragma unroll
  for (int m = 32; m >= 1; m >>= 1) { s += __shfl_xor(s, m); ss += __shfl_xor(ss, m); }
  __shared__ float red[8];
  __shared__ float lnv[256];
  const int wv = t >> 6;
  if ((t & 63) == 0) { red[wv] = s; red[4 + wv] = ss; }
  __syncthreads();
  const float S = red[0] + red[1] + red[2] + red[3];
  const float SS = red[4] + red[5] + red[6] + red[7];
  const float mean = S * (1.0f / ND);
  const float var = SS * (1.0f / ND) - mean * mean;
  const float rstd = rsqrtf(var + LNEPS);
  lnv[t] = (v - mean) * rstd * nsg[t] + nsb[t];
  if (t < 2) {
    const float p = sf[bk * 260 + 256 + t];
    pos[bk * 2 + t] = fminf(fmaxf(p, -1.0f), 1.0f);
    const float sc = sf[bk * 260 + 258 + t];
    scl[bk * 2 + t] = fminf(fmaxf(sc, 1e-3f), 2.0f);
  }
  __syncthreads();
  float acc = 0.f;
  for (int e = 0; e < ND; e++) acc = fmaf(lnv[e], wq[e * ND + t], acc);
  q[bk * ND + t] = acc;
}

// ---------------- fused grid_enc pass (bf16 MFMA) ----------------
// Block: 64 n-rows of one bk. Phase A: tln bf16 -> LDS. GEMM1: tln @ W1T -> h1
// (relu, bf16, XOR-swizzled LDS, aliases tln). GEMM2: h1 @ W2T -> o.
// mode 0: dots = (o + b2) . q / 16 ; mode 1: upd += attn_w . (o + b2)
#define LDA 264  // tln row stride (bf16): 132 words, %32=4 -> balanced b128 reads

__device__ __forceinline__ int h1idx(int row, int col) {
  // row stride 512 bf16 (=256 words, %32==0) would alias banks; swizzle 16B blocks
  return (row << 9) + ((((col >> 3) ^ (row & 7)) << 3) | (col & 7));
}

__global__ __launch_bounds__(256, 2) void k_fused_mfma(
    const float* __restrict__ kv,
    const float* __restrict__ pos, const float* __restrict__ scl,
    const float* __restrict__ gpw, const float* __restrict__ gpb,
    const float* __restrict__ lng, const float* __restrict__ lnb,
    const short* __restrict__ w1T, const float* __restrict__ b1,
    const short* __restrict__ w2T, const float* __restrict__ b2,
    const float* __restrict__ q, float* __restrict__ dots,
    const float* __restrict__ attn0, const float* __restrict__ denom,
    float* __restrict__ upd, const int mode) {
  __shared__ __align__(16) short smem[64 * 512];  // 64 KB; tln & h1 & dred alias
  short* tln = smem;
  short* h1 = smem;

  const int bk = blockIdx.y;
  const int n0 = blockIdx.x * 64;
  const int b = bk >> 3;
  const int t = threadIdx.x;
  const int wave = t >> 6;
  const int lane = t & 63;
  const int l15 = lane & 15;
  const int quad = lane >> 4;

  // ---- Phase A: tln = LN(kv + rel_enc) -> bf16 LDS ----
  {
    const float p0 = pos[bk * 2 + 0], p1 = pos[bk * 2 + 1];
    const float s0i = 1.0f / (scl[bk * 2 + 0] * 5.0f);
    const float s1i = 1.0f / (scl[bk * 2 + 1] * 5.0f);
    const int r = t >> 2;       // 0..63
    const int sub = t & 3;
    const int n = n0 + r;
    const float gx = -1.0f + GSTEP * (float)(n >> 5);
    const float gy = -1.0f + GSTEP * (float)(n & 31);
    const float rg0 = (gx - p0) * s0i;
    const float rg1 = (gy - p1) * s1i;
    const float* kvrow = kv + (size_t)(b * NN + n) * ND;
    float tv[64];
    float sum = 0.f, ssq = 0.f;
#pragma unroll
    for (int ii = 0; ii < 16; ii++) {
      const int d = sub * 4 + ii * 16;
      const float4 kv4 = *(const float4*)(kvrow + d);
      const float4 wa = *(const float4*)(gpw + d);
      const float4 wb = *(const float4*)(gpw + ND + d);
      const float4 pb = *(const float4*)(gpb + d);
      float v0 = kv4.x + rg0 * wa.x + rg1 * wb.x + pb.x;
      float v1 = kv4.y + rg0 * wa.y + rg1 * wb.y + pb.y;
      float v2 = kv4.z + rg0 * wa.z + rg1 * wb.z + pb.z;
      float v3 = kv4.w + rg0 * wa.w + rg1 * wb.w + pb.w;
      tv[ii * 4 + 0] = v0; sum += v0; ssq += v0 * v0;
      tv[ii * 4 + 1] = v1; sum += v1; ssq += v1 * v1;
      tv[ii * 4 + 2] = v2; sum += v2; ssq += v2 * v2;
      tv[ii * 4 + 3] = v3; sum += v3; ssq += v3 * v3;
    }
    sum += __shfl_xor(sum, 1); ssq += __shfl_xor(ssq, 1);
    sum += __shfl_xor(sum, 2); ssq += __shfl_xor(ssq, 2);
    const float mean = sum * (1.0f / ND);
    const float var = ssq * (1.0f / ND) - mean * mean;
    const float rstd = rsqrtf(var + LNEPS);
#pragma unroll
    for (int ii = 0; ii < 16; ii++) {
      const int d = sub * 4 + ii * 16;
      const float4 gg = *(const float4*)(lng + d);
      const float4 bb = *(const float4*)(lnb + d);
      short4v pk;
      pk.x = f2bf((tv[ii * 4 + 0] - mean) * rstd * gg.x + bb.x);
      pk.y = f2bf((tv[ii * 4 + 1] - mean) * rstd * gg.y + bb.y);
      pk.z = f2bf((tv[ii * 4 + 2] - mean) * rstd * gg.z + bb.z);
      pk.w = f2bf((tv[ii * 4 + 3] - mean) * rstd * gg.w + bb.w);
      *(short4v*)&tln[r * LDA + d] = pk;
    }
  }
  __syncthreads();

  // ---- GEMM1: h1 = relu(tln @ W1T^T + b1). Wave owns N1 cols [wave*128, +128) ----
  floatx4 acc1[4][8];
#pragma unroll
  for (int mt = 0; mt < 4; mt++)
#pragma unroll
    for (int nt = 0; nt < 8; nt++) acc1[mt][nt] = (floatx4){0.f, 0.f, 0.f, 0.f};

  const short* w1p = w1T + ((size_t)(wave * 128 + l15)) * 256 + quad * 8;
#pragma unroll
  for (int kk = 0; kk < 8; kk++) {
    short8 af[4];
#pragma unroll
    for (int mt = 0; mt < 4; mt++)
      af[mt] = *(const short8*)&tln[(mt * 16 + l15) * LDA + kk * 32 + quad * 8];
    short8 bf[8];
#pragma unroll
    for (int nt = 0; nt < 8; nt++)
      bf[nt] = *(const short8*)(w1p + nt * 16 * 256 + kk * 32);
#pragma unroll
    for (int mt = 0; mt < 4; mt++)
#pragma unroll
      for (int nt = 0; nt < 8; nt++)
        acc1[mt][nt] = __builtin_amdgcn_mfma_f32_16x16x32_bf16(af[mt], bf[nt], acc1[mt][nt], 0, 0, 0);
  }
  __syncthreads();  // all tln reads done before h1 overwrites

  {
    float b1v[8];
#pragma unroll
    for (int nt = 0; nt < 8; nt++) b1v[nt] = b1[wave * 128 + nt * 16 + l15];
#pragma unroll
    for (int mt = 0; mt < 4; mt++)
#pragma unroll
      for (int nt = 0; nt < 8; nt++) {
        const int col = wave * 128 + nt * 16 + l15;
#pragma unroll
        for (int j = 0; j < 4; j++) {
          const int row = mt * 16 + quad * 4 + j;
          h1[h1idx(row, col)] = f2bf(fmaxf(acc1[mt][nt][j] + b1v[nt], 0.f));
        }
      }
  }
  __syncthreads();

  // ---- GEMM2: o = h1 @ W2T^T (+b2 in epilogue). Wave owns N2 cols [wave*64, +64) ----
  floatx4 acc2[4][4];
#pragma unroll
  for (int mt = 0; mt < 4; mt++)
#pragma unroll
    for (int nt = 0; nt < 4; nt++) acc2[mt][nt] = (floatx4){0.f, 0.f, 0.f, 0.f};

  const short* w2p = w2T + ((size_t)(wave * 64 + l15)) * 512 + quad * 8;
#pragma unroll
  for (int kk = 0; kk < 16; kk++) {
    short8 af[4];
#pragma unroll
    for (int mt = 0; mt < 4; mt++) {
      const int row = mt * 16 + l15;
      af[mt] = *(const short8*)&h1[(row << 9) + (((kk * 4 + quad) ^ (row & 7)) << 3)];
    }
    short8 bf[4];
#pragma unroll
    for (int nt = 0; nt < 4; nt++)
      bf[nt] = *(const short8*)(w2p + nt * 16 * 512 + kk * 32);
#pragma unroll
    for (int mt = 0; mt < 4; mt++)
#pragma unroll
      for (int nt = 0; nt < 4; nt++)
        acc2[mt][nt] = __builtin_amdgcn_mfma_f32_16x16x32_bf16(af[mt], bf[nt], acc2[mt][nt], 0, 0, 0);
  }

  float b2v[4];
#pragma unroll
  for (int nt = 0; nt < 4; nt++) b2v[nt] = b2[wave * 64 + nt * 16 + l15];

  if (mode == 0) {
    float qn[4];
#pragma unroll
    for (int nt = 0; nt < 4; nt++) qn[nt] = q[bk * ND + wave * 64 + nt * 16 + l15];
    __syncthreads();  // done reading h1; reuse smem as float dred[4][64]
    float* dred = (float*)smem;
#pragma unroll
    for (int mt = 0; mt < 4; mt++)
#pragma unroll
      for (int j = 0; j < 4; j++) {
        float p = 0.f;
#pragma unroll
        for (int nt = 0; nt < 4; nt++)
          p = fmaf(acc2[mt][nt][j] + b2v[nt], qn[nt], p);
        p += __shfl_xor(p, 1); p += __shfl_xor(p, 2);
        p += __shfl_xor(p, 4); p += __shfl_xor(p, 8);
        if (l15 == 0) dred[wave * 64 + mt * 16 + quad * 4 + j] = p;
      }
    __syncthreads();
    if (t < 64) {
      const float s = dred[t] + dred[64 + t] + dred[128 + t] + dred[192 + t];
      dots[bk * NN + n0 + t] = s * 0.0625f;
    }
  } else {
    const float dn = 1.0f / denom[bk];
    float aw[4][4];
#pragma unroll
    for (int mt = 0; mt < 4; mt++)
#pragma unroll
      for (int j = 0; j < 4; j++)
        aw[mt][j] = (attn0[bk * NN + n0 + mt * 16 + quad * 4 + j] + EPSA) * dn;
#pragma unroll
    for (int nt = 0; nt < 4; nt++) {
      float s = 0.f;
#pragma unroll
      for (int mt = 0; mt < 4; mt++)
#pragma unroll
        for (int j = 0; j < 4; j++)
          s = fmaf(aw[mt][j], acc2[mt][nt][j] + b2v[nt], s);
      s += __shfl_xor(s, 16); s += __shfl_xor(s, 32);
      if (quad == 0) atomicAdd(upd + bk * ND + wave * 64 + nt * 16 + l15, s);
    }
  }
}

// ---------------- softmax over K per (b,n) ----------------
__global__ __launch_bounds__(256) void k_softmax(const float* __restrict__ dots,
                                                 float* __restrict__ attn0) {
  const int idx = blockIdx.x * 256 + threadIdx.x;
  const int b = idx >> 10, n = idx & 1023;
  float vals[NK];
  float mx = -1e30f;
#pragma unroll
  for (int k = 0; k < NK; k++) {
    vals[k] = dots[(size_t)(b * NK + k) * NN + n];
    mx = fmaxf(mx, vals[k]);
  }
  float s = 0.f;
#pragma unroll
  for (int k = 0; k < NK; k++) { vals[k] = expf(vals[k] - mx); s += vals[k]; }
  const float inv = 1.0f / s;
#pragma unroll
  for (int k = 0; k < NK; k++)
    attn0[(size_t)(b * NK + k) * NN + n] = vals[k] * inv;
}

// ---------------- attn0 row sums -> denom, pos_n ----------------
__global__ __launch_bounds__(256) void k_reduce1(const float* __restrict__ attn0,
                                                 float* __restrict__ sf,
                                                 float* __restrict__ denom) {
  const int bk = blockIdx.x, t = threadIdx.x;
  float S = 0.f, G0 = 0.f, G1 = 0.f;
#pragma unroll
  for (int i = 0; i < 4; i++) {
    const int n = t + 256 * i;
    const float a = attn0[(size_t)bk * NN + n];
    const float gx = -1.0f + GSTEP * (float)(n >> 5);
    const float gy = -1.0f + GSTEP * (float)(n & 31);
    S += a; G0 = fmaf(a, gx, G0); G1 = fmaf(a, gy, G1);
  }
#pragma unroll
  for (int m = 32; m >= 1; m >>= 1) {
    S += __shfl_xor(S, m); G0 += __shfl_xor(G0, m); G1 += __shfl_xor(G1, m);
  }
  __shared__ float red[12];
  const int wv = t >> 6;
  if ((t & 63) == 0) { red[wv] = S; red[4 + wv] = G0; red[8 + wv] = G1; }
  __syncthreads();
  if (t == 0) {
    const float St = red[0] + red[1] + red[2] + red[3];
    const float G0t = red[4] + red[5] + red[6] + red[7];
    const float G1t = red[8] + red[9] + red[10] + red[11];
    denom[bk] = St + (float)NN * EPSA;
    sf[bk * 260 + 256] = G0t;
    sf[bk * 260 + 257] = G1t;
  }
}

// ---------------- scl_n ----------------
__global__ __launch_bounds__(256) void k_reduce2(const float* __restrict__ attn0,
                                                 float* __restrict__ sf) {
  const int bk = blockIdx.x, t = threadIdx.x;
  const float p0 = sf[bk * 260 + 256];
  const float p1 = sf[bk * 260 + 257];
  float S0 = 0.f, S1 = 0.f;
#pragma unroll
  for (int i = 0; i < 4; i++) {
    const int n = t + 256 * i;
    const float w = attn0[(size_t)bk * NN + n] + EPSA;
    const float d0 = (-1.0f + GSTEP * (float)(n >> 5)) - p0;
    const float d1 = (-1.0f + GSTEP * (float)(n & 31)) - p1;
    S0 = fmaf(w, d0 * d0, S0);
    S1 = fmaf(w, d1 * d1, S1);
  }
#pragma unroll
  for (int m = 32; m >= 1; m >>= 1) { S0 += __shfl_xor(S0, m); S1 += __shfl_xor(S1, m); }
  __shared__ float red[8];
  const int wv = t >> 6;
  if ((t & 63) == 0) { red[wv] = S0; red[4 + wv] = S1; }
  __syncthreads();
  if (t == 0) {
    const float s0 = sqrtf(red[0] + red[1] + red[2] + red[3]);
    const float s1 = sqrtf(red[4] + red[5] + red[6] + red[7]);
    sf[bk * 260 + 258] = fminf(fmaxf(s0, 1e-3f), 2.0f);
    sf[bk * 260 + 259] = fminf(fmaxf(s1, 1e-3f), 2.0f);
  }
}

// ---------------- GRU slot update ----------------
__global__ __launch_bounds__(256) void k_gru(const float* __restrict__ upd,
                                             float* __restrict__ sf,
                                             const float* __restrict__ wih,
                                             const float* __restrict__ whh,
                                             const float* __restrict__ bih,
                                             const float* __restrict__ bhh) {
  const int bk = blockIdx.x, t = threadIdx.x;
  __shared__ float u[256], h[256];
  u[t] = upd[bk * ND + t];
  h[t] = sf[bk * 260 + t];
  __syncthreads();
  float g[6];
#pragma unroll
  for (int s = 0; s < 3; s++) {
    float ax = 0.f, ah = 0.f;
    const float* wi = wih + (size_t)(s * ND + t) * ND;
    const float* wh = whh + (size_t)(s * ND + t) * ND;
    for (int d = 0; d < ND; d++) {
      ax = fmaf(u[d], wi[d], ax);
      ah = fmaf(h[d], wh[d], ah);
    }
    g[s] = ax + bih[s * ND + t];
    g[3 + s] = ah + bhh[s * ND + t];
  }
  const float r = 1.0f / (1.0f + expf(-(g[0] + g[3])));
  const float z = 1.0f / (1.0f + expf(-(g[1] + g[4])));
  const float nn = tanhf(g[2] + r * g[5]);
  sf[bk * 260 + t] = (1.0f - z) * nn + z * h[t];
}

// ---------------- rel_grid output ----------------
__global__ __launch_bounds__(256) void k_relgrid(const float* __restrict__ pos,
                                                 const float* __restrict__ scl,
                                                 float* __restrict__ outr) {
  const int bk = blockIdx.x, t = threadIdx.x;
  const float p0 = pos[bk * 2 + 0], p1 = pos[bk * 2 + 1];
  const float s0 = scl[bk * 2 + 0] * 5.0f, s1 = scl[bk * 2 + 1] * 5.0f;
#pragma unroll
  for (int i = 0; i < 4; i++) {
    const int n = t + 256 * i;
    const float gx = -1.0f + GSTEP * (float)(n >> 5);
    const float gy = -1.0f + GSTEP * (float)(n & 31);
    float2 v;
    v.x = (gx - p0) / s0;
    v.y = (gy - p1) / s1;
    *(float2*)(outr + ((size_t)bk * NN + n) * 2) = v;
  }
}

// ---------------- final copies ----------------
__global__ __launch_bounds__(256) void k_copyout(const float* __restrict__ sf,
                                                 const float* __restrict__ attn0,
                                                 float* __restrict__ out) {
  const int i = blockIdx.x * 256 + threadIdx.x;
  if (i < 16640) out[i] = sf[i];
  if (i < 65536) out[16640 + i] = attn0[i];
}

extern "C" void kernel_launch(void* const* d_in, const int* in_sizes, int n_in,
                              void* d_out, int out_size, void* d_ws, size_t ws_size,
                              hipStream_t stream) {
  const float* inputs   = (const float*)d_in[0];
  const float* cond     = (const float*)d_in[1];
  const float* ni_g     = (const float*)d_in[2];
  const float* ni_b     = (const float*)d_in[3];
  const float* ns_g     = (const float*)d_in[4];
  const float* ns_b     = (const float*)d_in[5];
  const float* wq       = (const float*)d_in[6];
  const float* wk       = (const float*)d_in[7];
  const float* wv       = (const float*)d_in[8];
  const float* gp_w     = (const float*)d_in[9];
  const float* gp_b     = (const float*)d_in[10];
  const float* ge_ln_g  = (const float*)d_in[11];
  const float* ge_ln_b  = (const float*)d_in[12];
  const float* ge_w1    = (const float*)d_in[13];
  const float* ge_b1    = (const float*)d_in[14];
  const float* ge_w2    = (const float*)d_in[15];
  const float* ge_b2    = (const float*)d_in[16];
  const float* gru_wih  = (const float*)d_in[17];
  const float* gru_whh  = (const float*)d_in[18];
  const float* gru_bih  = (const float*)d_in[19];
  const float* gru_bhh  = (const float*)d_in[20];

  float* ws   = (float*)d_ws;
  float* kbuf = ws;                  // 8*1024*256
  float* vbuf = kbuf + 2097152;      // 8*1024*256
  float* sf   = vbuf + 2097152;      // 64*260
  float* qb   = sf + 16640;          // 64*256
  float* posb = qb + 16384;          // 64*2 (padded)
  float* sclb = posb + 128;          // 64*2 (padded)
  float* dotsb = sclb + 128;         // 64*1024
  float* at0  = dotsb + 65536;       // 64*1024
  float* denb = at0 + 65536;         // 64
  float* updb = denb + 64;           // 64*256
  float* statb = updb + 16384;       // 8192*2
  short* w1T  = (short*)(statb + 16384);  // 512*256 bf16
  short* w2T  = w1T + 131072;             // 256*512 bf16

  float* out = (float*)d_out;

  hipMemcpyAsync(sf, cond, 16640 * sizeof(float), hipMemcpyDeviceToDevice, stream);

  // bf16 transposed weights (once per launch)
  k_cvtT<<<512, 256, 0, stream>>>(ge_w1, w1T, 8, 255, 512);   // w1T[n1][k],  n1<512,k<256
  k_cvtT<<<512, 256, 0, stream>>>(ge_w2, w2T, 9, 511, 256);   // w2T[n2][k2], n2<256,k2<512

  k_ln_stats<<<NB * NN, 256, 0, stream>>>(inputs, statb);
  k_gemm_kv<<<dim3(128, 4, 2), 256, 0, stream>>>(inputs, statb, ni_g, ni_b, wk, wv, kbuf, vbuf);

  for (int s = 0; s < 4; s++) {
    k_prep<<<NBK, 256, 0, stream>>>(sf, ns_g, ns_b, wq, qb, posb, sclb);
    k_fused_mfma<<<dim3(16, NBK), 256, 0, stream>>>(
        kbuf, posb, sclb, gp_w, gp_b, ge_ln_g, ge_ln_b, w1T, ge_b1, w2T, ge_b2,
        qb, dotsb, nullptr, nullptr, nullptr, 0);
    k_softmax<<<32, 256, 0, stream>>>(dotsb, at0);
    k_reduce1<<<NBK, 256, 0, stream>>>(at0, sf, denb);
    k_reduce2<<<NBK, 256, 0, stream>>>(at0, sf);
    if (s < 3) {
      hipMemsetAsync(updb, 0, 16384 * sizeof(float), stream);
      k_fused_mfma<<<dim3(16, NBK), 256, 0, stream>>>(
          vbuf, posb, sclb, gp_w, gp_b, ge_ln_g, ge_ln_b, w1T, ge_b1, w2T, ge_b2,
          nullptr, nullptr, at0, denb, updb, 1);
      k_gru<<<NBK, 256, 0, stream>>>(updb, sf, gru_wih, gru_whh, gru_bih, gru_bhh);
    }
  }

  k_relgrid<<<NBK, 256, 0, stream>>>(posb, sclb, out + 16640 + 65536);
  k_copyout<<<256, 256, 0, stream>>>(sf, at0, out);
}